// Round 5
// baseline (4842.860 us; speedup 1.0000x reference)
//
#include <hip/hip_runtime.h>
#include <hip/hip_bf16.h>
#include <cstdint>
#include <cstddef>

// 3-layer LSTM (T=128, B=256, IN=512, H=1024/1024/512) — persistent kernel, round 12.
// vs round 9/10/11 (~3.8-4.0 ms; fences/inv/ring/warm/launch-per-phase ALL null):
// LDS-PIPE THEORY: all 16 waves of a block read IDENTICAL B-fragments from LDS
// (bslot depends on lane only). Per CU per phase that's 2048-2304 ds_read_b128
// x ~12 cyc on the CU's single LDS pipe = 10-11.5 µs — the dominant term, and
// the only one insensitive to every knob tried so far.
//  - ROW-PAIRED WAVES: each wave now owns 32 rows x 16 cols (2 row-tiles x 1
//    col-tile; waves 0-7 col-tile 0, waves 8-15 col-tile 1). One ds_read_b128
//    feeds TWO MFMAs -> LDS traffic HALVES (A: 10.2->5.1 µs, B: 11.5->5.7 µs).
//  - Per-element kc fold order unchanged => BIT-IDENTICAL output (absmax must
//    stay 0.00390625). l3 runs on waves 0-7 only (idle waves don't touch LDS).
//  - Sync scheme exactly r9 (validated): agent write-through h-stores,
//    pure-atomic barrier, 1 L2-inv/XCD/phase. Warm/ring-8 (r10) reverted.

typedef __attribute__((ext_vector_type(8))) short short8;
typedef __attribute__((ext_vector_type(4))) short short4v;
typedef __attribute__((ext_vector_type(4))) float floatx4;

#define NBLK 256
#define NTHR 1024

// ---------------- helpers ----------------
__device__ __forceinline__ float fsig(float x) {
    x = fminf(fmaxf(x, -30.f), 30.f);
    return 1.f / (1.f + __expf(-x));
}
__device__ __forceinline__ float ftanh(float x) {
    x = fminf(fmaxf(x, -15.f), 15.f);
    float e = __expf(2.f * x);
    return (e - 1.f) / (e + 1.f);
}

__device__ __forceinline__ int get_xcc() {
    int x;
    asm volatile("s_getreg_b32 %0, hwreg(HW_REG_XCC_ID)" : "=s"(x));
    return x & 7;
}

// sy layout (ints): xcc arrival counters @ x*64 (x<8); master @512; gen @576;
// census @640+x; safe-barrier arrival @704; safe-barrier flag @768;
// per-XCD epoch flags @832+x*16.

// One-time safe barrier (no XCD assumptions). Startup only.
__device__ __forceinline__ void safe_sync(int* sy) {
    __syncthreads();
    if (threadIdx.x == 0) {
        int a = __hip_atomic_fetch_add(sy + 704, 1, __ATOMIC_ACQ_REL, __HIP_MEMORY_SCOPE_AGENT);
        if (a == NBLK - 1)
            __hip_atomic_store(sy + 768, 1, __ATOMIC_RELEASE, __HIP_MEMORY_SCOPE_AGENT);
        while (__hip_atomic_load(sy + 768, __ATOMIC_RELAXED, __HIP_MEMORY_SCOPE_AGENT) == 0)
            __builtin_amdgcn_s_sleep(2);
        __builtin_amdgcn_fence(__ATOMIC_ACQUIRE, "agent");
    }
    __syncthreads();
}

// Phase barrier (r9-validated). Release: agent write-through h-stores complete at
// LLC before the entry __syncthreads drain -> relaxed arrivals, no wbl2.
// Acquire: per-XCD rank 0 does the full agent acquire fence (L2+L1 inv) and bumps
// the XCD epoch; others spin on the epoch and invalidate only their own L1.
__device__ __forceinline__ void grid_sync(int* sy, int myx, int myM, int G,
                                          int myr, int round) {
    __syncthreads();
    if (threadIdx.x == 0) {
        int* gen = sy + 576;
        int g = __hip_atomic_load(gen, __ATOMIC_RELAXED, __HIP_MEMORY_SCOPE_AGENT);
        int a = __hip_atomic_fetch_add(sy + myx * 64, 1, __ATOMIC_RELAXED, __HIP_MEMORY_SCOPE_AGENT);
        if ((a + 1) % myM == 0) {
            int m = __hip_atomic_fetch_add(sy + 512, 1, __ATOMIC_RELAXED, __HIP_MEMORY_SCOPE_AGENT);
            if ((m + 1) % G == 0)
                __hip_atomic_fetch_add(gen, 1, __ATOMIC_RELAXED, __HIP_MEMORY_SCOPE_AGENT);
        }
        while (__hip_atomic_load(gen, __ATOMIC_RELAXED, __HIP_MEMORY_SCOPE_AGENT) == g)
            __builtin_amdgcn_s_sleep(2);
        int* ep = sy + 832 + myx * 16;
        if (myr == 0) {
            __builtin_amdgcn_fence(__ATOMIC_ACQUIRE, "agent");   // L2 inv (one per XCD)
            __hip_atomic_store(ep, round, __ATOMIC_RELEASE, __HIP_MEMORY_SCOPE_AGENT);
        } else {
            while (__hip_atomic_load(ep, __ATOMIC_RELAXED, __HIP_MEMORY_SCOPE_AGENT) < round)
                __builtin_amdgcn_s_sleep(1);
            asm volatile("buffer_inv sc0\n\ts_waitcnt vmcnt(0)" ::: "memory");  // own L1 only
        }
    }
    __syncthreads();
}

// ---------------- pack kernels ----------------
// Frag-ordered weight pack: dst[tile][kc][slot] of short8, 16 cols per tile.
// slot = lane: du=slot&3, g=(slot>>2)&3, ksub=slot>>4. unit = tile*4+du.
template<int K1, int K2, int H>
__global__ void pack_frag_kernel(const float* __restrict__ Wih,
                                 const float* __restrict__ Whh,
                                 __hip_bfloat16* __restrict__ dst) {
    constexpr int NK = (K1 + K2) / 32;
    constexpr int NTT = H / 4;
    int idx = blockIdx.x * 256 + threadIdx.x;
    if (idx >= NTT * NK * 64) return;
    int slot = idx & 63;
    int kc = (idx >> 6) % NK;
    int b = idx / (64 * NK);
    int du = slot & 3, g = (slot >> 2) & 3, ksub = slot >> 4;
    int unit = b * 4 + du;
    int j = g * H + unit;
    int k0 = kc * 32 + ksub * 8;
    __hip_bfloat16 tmp[8];
#pragma unroll
    for (int e = 0; e < 8; ++e) {
        int k = k0 + e;
        float v = (k < K1) ? Wih[(size_t)j * K1 + k] : Whh[(size_t)j * K2 + (k - K1)];
        tmp[e] = __float2bfloat16(v);
    }
    *(short8*)(dst + (size_t)idx * 8) = *(short8*)tmp;
}

__global__ void pack_bias_kernel(const float* __restrict__ a,
                                 const float* __restrict__ b,
                                 int n, float* __restrict__ out) {
    int i = blockIdx.x * 256 + threadIdx.x;
    if (i < n) out[i] = a[i] + b[i];
}

// x[t][row][512] fp32 -> xs[t][s 0..63][row][8] bf16 (8-wide slabs).
__global__ void x_to_slab_kernel(const float* __restrict__ x,
                                 __hip_bfloat16* __restrict__ xs) {
    int idx = blockIdx.x * 256 + threadIdx.x;
    int j   = idx & 7;
    int row = (idx >> 3) & 255;
    int s   = (idx >> 11) & 63;
    int t   = idx >> 17;
    xs[idx] = __float2bfloat16(x[((size_t)(t * 256 + row)) * 512 + s * 8 + j]);
}

__global__ void zero_f32_kernel(float* p, int n) {
    int i = blockIdx.x * 256 + threadIdx.x;
    if (i < n) p[i] = 0.f;
}

__global__ void zero_i32_kernel(int* p, int n) {
    int i = blockIdx.x * 256 + threadIdx.x;
    if (i < n) p[i] = 0;
}

// ---------------- A-fragment loaders ----------------
__device__ __forceinline__ short8 afrag8(const __hip_bfloat16* __restrict__ base, int k) {
    return *(const short8*)(base + (size_t)k * 8192);
}
__device__ __forceinline__ short8 afrag4(const __hip_bfloat16* __restrict__ base, int k) {
    const __hip_bfloat16* p = base + (size_t)k * 8192;
    short4v lo = *(const short4v*)p;
    short4v hi = *(const short4v*)(p + 1024);
    return (short8){lo.x, lo.y, lo.z, lo.w, hi.x, hi.y, hi.z, hi.w};
}

// ---------------- per-layer GEMM + fused cell (row-paired waves) ----------------
// Each wave: 32 rows (2 row-tiles) x 16 cols (its col-tile myti). One ds_read_b128
// per kc feeds both row-tiles' MFMAs. bslot0 passed pre-offset with myti*TSTR.
template<int NK1, int NK2, bool A2W4, int NCT, int H>
__device__ __forceinline__ void run_layer(
    const short8* __restrict__ ldsw, int bslot0,
    const __hip_bfloat16* __restrict__ A1, const __hip_bfloat16* __restrict__ A2,
    float bl,
    __hip_bfloat16* __restrict__ hs, int slab,
    float (&creg)[2][4], int tbase, int lane, int wave, int myti,
    bool fin, float* __restrict__ ho, float* __restrict__ co)
{
    constexpr int NK = NK1 + NK2;
    constexpr int W = NCT * 4;
    const int col = lane & 15, ksub = lane >> 4;
    const int rg = wave & 7;
    const int r0 = rg * 32 + col;     // row-tile 0 row for this lane
    const __hip_bfloat16* __restrict__ a1_0 = A1 + ksub * 2048 + r0 * 8;
    const __hip_bfloat16* __restrict__ a1_1 = a1_0 + 16 * 8;
    const __hip_bfloat16* __restrict__ a2_0 = A2 + ksub * 2048 + (A2W4 ? r0 * 4 : r0 * 8);
    const __hip_bfloat16* __restrict__ a2_1 = a2_0 + (A2W4 ? 16 * 4 : 16 * 8);

    short8 rb0[4], rb1[4];
#pragma unroll
    for (int i = 0; i < 4; ++i) {     // NK1 >= 16 >= 4 always
        rb0[i] = afrag8(a1_0, i);
        rb1[i] = afrag8(a1_1, i);
    }

    floatx4 acc0 = (floatx4){0.f, 0.f, 0.f, 0.f};
    floatx4 acc1 = (floatx4){0.f, 0.f, 0.f, 0.f};

#pragma unroll 4
    for (int kc = 0; kc < NK; ++kc) {
        short8 b = ldsw[bslot0 + kc * 64];
        acc0 = __builtin_amdgcn_mfma_f32_16x16x32_bf16(rb0[kc & 3], b, acc0, 0, 0, 0);
        acc1 = __builtin_amdgcn_mfma_f32_16x16x32_bf16(rb1[kc & 3], b, acc1, 0, 0, 0);
        int kn = kc + 4;
        if (kn < NK) {
            rb0[kc & 3] = (kn < NK1) ? afrag8(a1_0, kn)
                         : (A2W4 ? afrag4(a2_0, kn - NK1) : afrag8(a2_0, kn - NK1));
            rb1[kc & 3] = (kn < NK1) ? afrag8(a1_1, kn)
                         : (A2W4 ? afrag4(a2_1, kn - NK1) : afrag8(a2_1, kn - NK1));
        }
    }

    // epilogue per row-tile: C/D layout col=lane&15, row=(lane>>4)*4+r.
    const int du = col & 3;
    const int sbase = ksub * 16 + du;
#pragma unroll
    for (int rt = 0; rt < 2; ++rt) {
        const floatx4 acc = rt ? acc1 : acc0;
        float avb[4];
#pragma unroll
        for (int r = 0; r < 4; ++r) avb[r] = acc[r] + bl;
#pragma unroll
        for (int r = 0; r < 4; ++r) {
            float gI = __shfl(avb[r], sbase);
            float gF = __shfl(avb[r], sbase + 4);
            float gG = __shfl(avb[r], sbase + 8);
            float gO = __shfl(avb[r], sbase + 12);
            float i_ = fsig(gI), f_ = fsig(gF), gg = ftanh(gG), o_ = fsig(gO);
            float cn = f_ * creg[rt][r] + i_ * gg;
            creg[rt][r] = cn;
            float hn = o_ * ftanh(cn);
            // pack two adjacent units into one 4B agent-scope (LLC write-through)
            // store: lanes col 0/2 store {col, col+1}.
            __hip_bfloat16 hv = __float2bfloat16(hn);
            unsigned hb = (unsigned)*reinterpret_cast<unsigned short*>(&hv);
            unsigned hp = __shfl(hb, lane + 1);
            int orow = rg * 32 + rt * 16 + ksub * 4 + r;
            if (col < 4) {
                if ((col & 1) == 0) {
                    unsigned pk = hb | (hp << 16);
                    size_t idx = ((size_t)slab * 256 + orow) * W + myti * 4 + col;
                    __hip_atomic_store((unsigned*)(hs + idx), pk,
                                       __ATOMIC_RELAXED, __HIP_MEMORY_SCOPE_AGENT);
                }
                if (fin) {
                    int unit = (tbase + myti) * 4 + du;
                    ho[(size_t)orow * H + unit] = hn;
                    co[(size_t)orow * H + unit] = cn;
                }
            }
        }
    }
}

// ---------------- persistent kernel ----------------
__global__ __launch_bounds__(NTHR, 4) void lstm_persistent(
    const __hip_bfloat16* __restrict__ xs,
    const __hip_bfloat16* __restrict__ w1f,
    const __hip_bfloat16* __restrict__ w2f,
    const __hip_bfloat16* __restrict__ w3f,
    const float* __restrict__ bc1, const float* __restrict__ bc2, const float* __restrict__ bc3,
    __hip_bfloat16* __restrict__ h1b, __hip_bfloat16* __restrict__ h2b,
    __hip_bfloat16* __restrict__ h3b,
    float* __restrict__ out, int* syncp)
{
    __shared__ short8 ldsw[9216];   // A: w2 2 tiles [0,8192). B: w1 2 tiles [0,6144) + w3 [6144,9216)
    __shared__ int smeta[4];        // [0]=xcc, [1]=myM, [2]=myrank
    const int tid = threadIdx.x, blk = blockIdx.x;
    const int lane = tid & 63, wave = tid >> 6;
    const bool isA = blk < 128;
    const int sb = isA ? blk : (blk - 128);

    if (isA) {
        const short8* s2 = (const short8*)w2f + (size_t)sb * 8192;
        for (int i = tid; i < 8192; i += NTHR) ldsw[i] = s2[i];
    } else {
        const short8* s1 = (const short8*)w1f + (size_t)sb * 6144;
        for (int i = tid; i < 6144; i += NTHR) ldsw[i] = s1[i];
        const short8* s3 = (const short8*)w3f + (size_t)sb * 3072;
        for (int i = tid; i < 3072; i += NTHR) ldsw[6144 + i] = s3[i];
    }

    // census: discover this block's XCD, per-XCD arrival counts, and XCD rank
    if (tid == 0) {
        int myx = get_xcc();
        int r = __hip_atomic_fetch_add(syncp + 640 + myx, 1, __ATOMIC_RELAXED, __HIP_MEMORY_SCOPE_AGENT);
        smeta[0] = myx;
        smeta[2] = r;
    }
    safe_sync(syncp);
    if (tid == 0) {
        int myx = smeta[0];
        int m = __hip_atomic_load(syncp + 640 + myx, __ATOMIC_RELAXED, __HIP_MEMORY_SCOPE_AGENT);
        int G = 0;
        for (int x = 0; x < 8; ++x)
            G += (__hip_atomic_load(syncp + 640 + x, __ATOMIC_RELAXED, __HIP_MEMORY_SCOPE_AGENT) > 0);
        if (m < 1) m = 1;
        if (G < 1) G = 1;
        smeta[1] = m;
        smeta[3] = G;
    }
    __syncthreads();
    const int myx_a = smeta[0];
    const int myM_a = smeta[1];
    const int myr_a = smeta[2];
    const int G_a   = smeta[3];

    const int col = lane & 15, du = col & 3, g = col >> 2;
    const int myti = wave >> 3;

    float bl1 = 0.f, bl2 = 0.f, bl3 = 0.f;
    if (isA) {
        bl2 = bc2[g * 1024 + (2 * sb + myti) * 4 + du];
    } else {
        bl1 = bc1[g * 1024 + (2 * sb + myti) * 4 + du];
        bl3 = bc3[g * 512 + sb * 4 + du];          // used by waves 0-7 only
    }

    float c1r[2][4] = {{0.f,0.f,0.f,0.f},{0.f,0.f,0.f,0.f}};
    float c2r[2][4] = {{0.f,0.f,0.f,0.f},{0.f,0.f,0.f,0.f}};
    float c3r[2][4] = {{0.f,0.f,0.f,0.f},{0.f,0.f,0.f,0.f}};

    float* h1o = out;
    float* c1o = out + 262144;
    float* h2o = out + 524288;
    float* c2o = out + 786432;
    float* h3o = out + 1048576;
    float* c3o = out + 1179648;

    // prologue: group B runs l1(0): A=[x(0) | h1(-1)=0(buf1)] -> h1(0) buf0.
    if (!isA) {
        run_layer<16, 32, false, 2, 1024>(ldsw, lane + myti * 3072,
            xs, h1b + 262144, bl1, h1b, sb, c1r, 2 * sb, lane, wave, myti,
            false, h1o, c1o);
    }
    grid_sync(syncp, myx_a, myM_a, G_a, myr_a, 1);

    // phase(t): groupA: l2(t); groupB: l1(t+1), l3(t-1); barrier (1 L2-inv/XCD).
    for (int t = 0; t < 128; ++t) {
        const size_t cur = (size_t)(t & 1), prv = (size_t)((t + 1) & 1);
        if (isA) {
            run_layer<32, 32, false, 2, 1024>(ldsw, lane + myti * 4096,
                h1b + cur * 262144, h2b + prv * 262144, bl2,
                h2b + cur * 262144, sb, c2r, 2 * sb, lane, wave, myti,
                t == 127, h2o, c2o);
        } else {
            if (t < 127) {
                run_layer<16, 32, false, 2, 1024>(ldsw, lane + myti * 3072,
                    xs + (size_t)(t + 1) * 131072, h1b + cur * 262144, bl1,
                    h1b + prv * 262144, sb, c1r, 2 * sb, lane, wave, myti,
                    (t + 1) == 127, h1o, c1o);
            }
            if (t >= 1 && wave < 8) {
                run_layer<32, 16, true, 1, 512>(ldsw, 6144 + lane,
                    h2b + prv * 262144, h3b + cur * 131072, bl3,
                    h3b + prv * 131072, sb, c3r, sb, lane, wave, 0,
                    false, h3o, c3o);
            }
        }
        grid_sync(syncp, myx_a, myM_a, G_a, myr_a, t + 2);
    }

    // epilogue: group B: l3(127): A=[h2(127)(buf1) | h3(126)(buf0)] -> h3(127), final
    if (!isA && wave < 8) {
        run_layer<32, 16, true, 1, 512>(ldsw, 6144 + lane,
            h2b + 262144, h3b, bl3, h3b + 131072, sb, c3r, sb, lane, wave, 0,
            true, h3o, c3o);
    }
}

// ---------------- launch ----------------
extern "C" void kernel_launch(void* const* d_in, const int* in_sizes, int n_in,
                              void* d_out, int out_size, void* d_ws, size_t ws_size,
                              hipStream_t stream) {
    const float* x    = (const float*)d_in[0];
    const float* Wih1 = (const float*)d_in[1];
    const float* Whh1 = (const float*)d_in[2];
    const float* bih1 = (const float*)d_in[3];
    const float* bhh1 = (const float*)d_in[4];
    const float* Wih2 = (const float*)d_in[5];
    const float* Whh2 = (const float*)d_in[6];
    const float* bih2 = (const float*)d_in[7];
    const float* bhh2 = (const float*)d_in[8];
    const float* Wih3 = (const float*)d_in[9];
    const float* Whh3 = (const float*)d_in[10];
    const float* bih3 = (const float*)d_in[11];
    const float* bhh3 = (const float*)d_in[12];
    float* out = (float*)d_out;

    char* p = (char*)d_ws;
    auto alloc = [&](size_t bytes) {
        char* r = p;
        p += (bytes + 255) & ~(size_t)255;
        return r;
    };
    __hip_bfloat16* xs  = (__hip_bfloat16*)alloc((size_t)128 * 64 * 256 * 8 * 2);
    __hip_bfloat16* w1f = (__hip_bfloat16*)alloc((size_t)256 * 48 * 64 * 8 * 2);
    __hip_bfloat16* w2f = (__hip_bfloat16*)alloc((size_t)256 * 64 * 64 * 8 * 2);
    __hip_bfloat16* w3f = (__hip_bfloat16*)alloc((size_t)128 * 48 * 64 * 8 * 2);
    float* bc1 = (float*)alloc(4096 * 4);
    float* bc2 = (float*)alloc(4096 * 4);
    float* bc3 = (float*)alloc(2048 * 4);
    __hip_bfloat16* h1b = (__hip_bfloat16*)alloc((size_t)2 * 262144 * 2);
    __hip_bfloat16* h2b = (__hip_bfloat16*)alloc((size_t)2 * 262144 * 2);
    __hip_bfloat16* h3b = (__hip_bfloat16*)alloc((size_t)2 * 131072 * 2);
    int* syncp = (int*)alloc(4096);

    auto blocks = [](int n) { return (n + 255) / 256; };

    pack_frag_kernel<512, 1024, 1024><<<blocks(256 * 48 * 64), 256, 0, stream>>>(Wih1, Whh1, w1f);
    pack_frag_kernel<1024, 1024, 1024><<<blocks(256 * 64 * 64), 256, 0, stream>>>(Wih2, Whh2, w2f);
    pack_frag_kernel<1024, 512, 512><<<blocks(128 * 48 * 64), 256, 0, stream>>>(Wih3, Whh3, w3f);
    pack_bias_kernel<<<blocks(4096), 256, 0, stream>>>(bih1, bhh1, 4096, bc1);
    pack_bias_kernel<<<blocks(4096), 256, 0, stream>>>(bih2, bhh2, 4096, bc2);
    pack_bias_kernel<<<blocks(2048), 256, 0, stream>>>(bih3, bhh3, 2048, bc3);
    x_to_slab_kernel<<<blocks(128 * 256 * 512), 256, 0, stream>>>(x, xs);
    zero_f32_kernel<<<blocks(262144), 256, 0, stream>>>((float*)h1b, 262144);
    zero_f32_kernel<<<blocks(262144), 256, 0, stream>>>((float*)h2b, 262144);
    zero_f32_kernel<<<blocks(131072), 256, 0, stream>>>((float*)h3b, 131072);
    zero_i32_kernel<<<1, 1024, 0, stream>>>(syncp, 1024);

    lstm_persistent<<<NBLK, NTHR, 0, stream>>>(xs, w1f, w2f, w3f, bc1, bc2, bc3,
                                               h1b, h2b, h3b, out, syncp);
}

// Round 6
// 3618.747 us; speedup vs baseline: 1.3383x; 1.3383x over previous
//
#include <hip/hip_runtime.h>
#include <hip/hip_bf16.h>
#include <cstdint>
#include <cstddef>

// 3-layer LSTM (T=128, B=256, IN=512, H=1024/1024/512) — persistent kernel, round 13.
// Model (fits ALL rounds 6-12): phase time ≈ fabric-miss lines/XCD × latency / MSHRs
// ≈ 24K lines × 400cyc / 128 ≈ 31 µs. Levers: fewer lines, no drain between phases.
//  - 8-SLOT ROTATING ARENA for h1/h2/h3 (addr slot = s&7): no stale-L2 aliasing
//    within 8 generations -> L2-inv only every 4th phase -> x-slab/weights survive
//    in L2 across 4-phase windows (kills the 256KB/XCD/phase x refetch).
//  - DATAFLOW FLAGS instead of per-phase global barrier: done1/done2/done3[t]
//    absolute-phase counters (no reuse). A(t) waits {done1[t], done2[t-1]};
//    B l1(t+1) waits done1[t] only (self-chain, runs ahead of A); B l3(t-1)
//    waits {done2[t-1], done3[t-2]}. Phases overlap; miss pipeline stays fed.
//  - Full rendezvous + L2-inv every 4 phases bounds skew (<4) << slot distance (8).
//  - Per-wait L1-only buffer_inv sc0 (cheap); agent write-through h-stores
//    unchanged (r8/r9-validated release path).
//  - Compute core reverted to r9 exactly (NT=2, ring-4) => bit-identical output
//    required (absmax 0.00390625).

typedef __attribute__((ext_vector_type(8))) short short8;
typedef __attribute__((ext_vector_type(4))) short short4v;
typedef __attribute__((ext_vector_type(4))) float floatx4;

#define NBLK 256
#define NTHR 1024

// ---------------- helpers ----------------
__device__ __forceinline__ float fsig(float x) {
    x = fminf(fmaxf(x, -30.f), 30.f);
    return 1.f / (1.f + __expf(-x));
}
__device__ __forceinline__ float ftanh(float x) {
    x = fminf(fmaxf(x, -15.f), 15.f);
    float e = __expf(2.f * x);
    return (e - 1.f) / (e + 1.f);
}

__device__ __forceinline__ int get_xcc() {
    int x;
    asm volatile("s_getreg_b32 %0, hwreg(HW_REG_XCC_ID)" : "=s"(x));
    return x & 7;
}

__device__ __forceinline__ void l1_inv() {
    asm volatile("buffer_inv sc0\n\ts_waitcnt vmcnt(0)" ::: "memory");
}

__device__ __forceinline__ void wait_cnt(int* c, int target) {
    while (__hip_atomic_load(c, __ATOMIC_RELAXED, __HIP_MEMORY_SCOPE_AGENT) < target)
        __builtin_amdgcn_s_sleep(1);
}

__device__ __forceinline__ void signal_cnt(int* c) {
    __hip_atomic_fetch_add(c, 1, __ATOMIC_RELAXED, __HIP_MEMORY_SCOPE_AGENT);
}

// sy layout (ints): xcc arrival @ x*64; master @512; gen @576; census @640+x;
// safe-barrier arrival @704 / flag @768; epoch @832+x*16;
// done1 @1024+t, done2 @1280+t, done3 @1536+t (t in [0,130]).

// One-time safe barrier (no XCD assumptions). Startup only.
__device__ __forceinline__ void safe_sync(int* sy) {
    __syncthreads();
    if (threadIdx.x == 0) {
        int a = __hip_atomic_fetch_add(sy + 704, 1, __ATOMIC_ACQ_REL, __HIP_MEMORY_SCOPE_AGENT);
        if (a == NBLK - 1)
            __hip_atomic_store(sy + 768, 1, __ATOMIC_RELEASE, __HIP_MEMORY_SCOPE_AGENT);
        while (__hip_atomic_load(sy + 768, __ATOMIC_RELAXED, __HIP_MEMORY_SCOPE_AGENT) == 0)
            __builtin_amdgcn_s_sleep(2);
        __builtin_amdgcn_fence(__ATOMIC_ACQUIRE, "agent");
    }
    __syncthreads();
}

// Full rendezvous barrier (every 4th phase): pure-atomic generation barrier +
// per-XCD single L2 inv (rank0 agent acquire fence) + L1 inv for the rest.
__device__ __forceinline__ void grid_sync(int* sy, int myx, int myM, int G,
                                          int myr, int round) {
    __syncthreads();
    if (threadIdx.x == 0) {
        int* gen = sy + 576;
        int g = __hip_atomic_load(gen, __ATOMIC_RELAXED, __HIP_MEMORY_SCOPE_AGENT);
        int a = __hip_atomic_fetch_add(sy + myx * 64, 1, __ATOMIC_RELAXED, __HIP_MEMORY_SCOPE_AGENT);
        if ((a + 1) % myM == 0) {
            int m = __hip_atomic_fetch_add(sy + 512, 1, __ATOMIC_RELAXED, __HIP_MEMORY_SCOPE_AGENT);
            if ((m + 1) % G == 0)
                __hip_atomic_fetch_add(gen, 1, __ATOMIC_RELAXED, __HIP_MEMORY_SCOPE_AGENT);
        }
        while (__hip_atomic_load(gen, __ATOMIC_RELAXED, __HIP_MEMORY_SCOPE_AGENT) == g)
            __builtin_amdgcn_s_sleep(2);
        int* ep = sy + 832 + myx * 16;
        if (myr == 0) {
            __builtin_amdgcn_fence(__ATOMIC_ACQUIRE, "agent");   // L2+L1 inv (one per XCD)
            __hip_atomic_store(ep, round, __ATOMIC_RELEASE, __HIP_MEMORY_SCOPE_AGENT);
        } else {
            while (__hip_atomic_load(ep, __ATOMIC_RELAXED, __HIP_MEMORY_SCOPE_AGENT) < round)
                __builtin_amdgcn_s_sleep(1);
            l1_inv();
        }
    }
    __syncthreads();
}

// ---------------- pack kernels ----------------
template<int K1, int K2, int H>
__global__ void pack_frag_kernel(const float* __restrict__ Wih,
                                 const float* __restrict__ Whh,
                                 __hip_bfloat16* __restrict__ dst) {
    constexpr int NK = (K1 + K2) / 32;
    constexpr int NTT = H / 4;
    int idx = blockIdx.x * 256 + threadIdx.x;
    if (idx >= NTT * NK * 64) return;
    int slot = idx & 63;
    int kc = (idx >> 6) % NK;
    int b = idx / (64 * NK);
    int du = slot & 3, g = (slot >> 2) & 3, ksub = slot >> 4;
    int unit = b * 4 + du;
    int j = g * H + unit;
    int k0 = kc * 32 + ksub * 8;
    __hip_bfloat16 tmp[8];
#pragma unroll
    for (int e = 0; e < 8; ++e) {
        int k = k0 + e;
        float v = (k < K1) ? Wih[(size_t)j * K1 + k] : Whh[(size_t)j * K2 + (k - K1)];
        tmp[e] = __float2bfloat16(v);
    }
    *(short8*)(dst + (size_t)idx * 8) = *(short8*)tmp;
}

__global__ void pack_bias_kernel(const float* __restrict__ a,
                                 const float* __restrict__ b,
                                 int n, float* __restrict__ out) {
    int i = blockIdx.x * 256 + threadIdx.x;
    if (i < n) out[i] = a[i] + b[i];
}

__global__ void x_to_slab_kernel(const float* __restrict__ x,
                                 __hip_bfloat16* __restrict__ xs) {
    int idx = blockIdx.x * 256 + threadIdx.x;
    int j   = idx & 7;
    int row = (idx >> 3) & 255;
    int s   = (idx >> 11) & 63;
    int t   = idx >> 17;
    xs[idx] = __float2bfloat16(x[((size_t)(t * 256 + row)) * 512 + s * 8 + j]);
}

__global__ void zero_f32_kernel(float* p, int n) {
    int i = blockIdx.x * 256 + threadIdx.x;
    if (i < n) p[i] = 0.f;
}

__global__ void zero_i32_kernel(int* p, int n) {
    int i = blockIdx.x * 256 + threadIdx.x;
    if (i < n) p[i] = 0;
}

// ---------------- A-fragment loaders ----------------
__device__ __forceinline__ short8 afrag8(const __hip_bfloat16* __restrict__ base, int k) {
    return *(const short8*)(base + (size_t)k * 8192);
}
__device__ __forceinline__ short8 afrag4(const __hip_bfloat16* __restrict__ base, int k) {
    const __hip_bfloat16* p = base + (size_t)k * 8192;
    short4v lo = *(const short4v*)p;
    short4v hi = *(const short4v*)(p + 1024);
    return (short8){lo.x, lo.y, lo.z, lo.w, hi.x, hi.y, hi.z, hi.w};
}

// ---------------- per-layer GEMM + fused cell (r9 core, bit-exact) ----------------
template<int NK1, int NK2, bool A2W4, int NT, int H, int TSTR>
__device__ __forceinline__ void run_layer(
    const short8* __restrict__ ldsw, int bslot0,
    const __hip_bfloat16* __restrict__ A1, const __hip_bfloat16* __restrict__ A2,
    const float (&bl)[NT],
    __hip_bfloat16* __restrict__ hs, int slab,
    float (&creg)[NT][4], int tbase, int lane, int wave,
    bool fin, float* __restrict__ ho, float* __restrict__ co)
{
    constexpr int NK = NK1 + NK2;
    constexpr int W = NT * 4;
    const int col = lane & 15, ksub = lane >> 4;
    const int row = wave * 16 + col;
    const __hip_bfloat16* __restrict__ a1 = A1 + ksub * 2048 + row * 8;
    const __hip_bfloat16* __restrict__ a2 = A2 + ksub * 2048 + (A2W4 ? row * 4 : row * 8);

    short8 rb[4];
#pragma unroll
    for (int i = 0; i < 4; ++i) rb[i] = afrag8(a1, i);

    floatx4 acc[NT];
#pragma unroll
    for (int ti = 0; ti < NT; ++ti) acc[ti] = (floatx4){0.f, 0.f, 0.f, 0.f};

#pragma unroll 4
    for (int kc = 0; kc < NK; ++kc) {
#pragma unroll
        for (int ti = 0; ti < NT; ++ti)
            acc[ti] = __builtin_amdgcn_mfma_f32_16x16x32_bf16(
                rb[kc & 3], ldsw[bslot0 + ti * TSTR + kc * 64], acc[ti], 0, 0, 0);
        int kn = kc + 4;
        if (kn < NK)
            rb[kc & 3] = (kn < NK1) ? afrag8(a1, kn)
                        : (A2W4 ? afrag4(a2, kn - NK1) : afrag8(a2, kn - NK1));
    }

    const int du = col & 3;
    const int sbase = ksub * 16 + du;
#pragma unroll
    for (int ti = 0; ti < NT; ++ti) {
        float avb[4];
#pragma unroll
        for (int r = 0; r < 4; ++r) avb[r] = acc[ti][r] + bl[ti];
#pragma unroll
        for (int r = 0; r < 4; ++r) {
            float gI = __shfl(avb[r], sbase);
            float gF = __shfl(avb[r], sbase + 4);
            float gG = __shfl(avb[r], sbase + 8);
            float gO = __shfl(avb[r], sbase + 12);
            float i_ = fsig(gI), f_ = fsig(gF), gg = ftanh(gG), o_ = fsig(gO);
            float cn = f_ * creg[ti][r] + i_ * gg;
            creg[ti][r] = cn;
            float hn = o_ * ftanh(cn);
            __hip_bfloat16 hv = __float2bfloat16(hn);
            unsigned hb = (unsigned)*reinterpret_cast<unsigned short*>(&hv);
            unsigned hp = __shfl(hb, lane + 1);
            int orow = wave * 16 + ksub * 4 + r;
            if (col < 4) {
                if ((col & 1) == 0) {
                    unsigned pk = hb | (hp << 16);
                    size_t idx = ((size_t)slab * 256 + orow) * W + ti * 4 + col;
                    __hip_atomic_store((unsigned*)(hs + idx), pk,
                                       __ATOMIC_RELAXED, __HIP_MEMORY_SCOPE_AGENT);
                }
                if (fin) {
                    int unit = (tbase + ti) * 4 + du;
                    ho[(size_t)orow * H + unit] = hn;
                    co[(size_t)orow * H + unit] = cn;
                }
            }
        }
    }
}

// ---------------- persistent kernel ----------------
__global__ __launch_bounds__(NTHR, 4) void lstm_persistent(
    const __hip_bfloat16* __restrict__ xs,
    const __hip_bfloat16* __restrict__ w1f,
    const __hip_bfloat16* __restrict__ w2f,
    const __hip_bfloat16* __restrict__ w3f,
    const float* __restrict__ bc1, const float* __restrict__ bc2, const float* __restrict__ bc3,
    __hip_bfloat16* __restrict__ h1a, __hip_bfloat16* __restrict__ h2a,
    __hip_bfloat16* __restrict__ h3a,
    float* __restrict__ out, int* syncp)
{
    __shared__ short8 ldsw[9216];
    __shared__ int smeta[4];
    const int tid = threadIdx.x, blk = blockIdx.x;
    const int lane = tid & 63, wave = tid >> 6;
    const bool isA = blk < 128;
    const int sb = isA ? blk : (blk - 128);

    if (isA) {
        const short8* s2 = (const short8*)w2f + (size_t)sb * 8192;
        for (int i = tid; i < 8192; i += NTHR) ldsw[i] = s2[i];
    } else {
        const short8* s1 = (const short8*)w1f + (size_t)sb * 6144;
        for (int i = tid; i < 6144; i += NTHR) ldsw[i] = s1[i];
        const short8* s3 = (const short8*)w3f + (size_t)sb * 3072;
        for (int i = tid; i < 3072; i += NTHR) ldsw[6144 + i] = s3[i];
    }

    // census
    if (tid == 0) {
        int myx = get_xcc();
        int r = __hip_atomic_fetch_add(syncp + 640 + myx, 1, __ATOMIC_RELAXED, __HIP_MEMORY_SCOPE_AGENT);
        smeta[0] = myx;
        smeta[2] = r;
    }
    safe_sync(syncp);
    if (tid == 0) {
        int myx = smeta[0];
        int m = __hip_atomic_load(syncp + 640 + myx, __ATOMIC_RELAXED, __HIP_MEMORY_SCOPE_AGENT);
        int G = 0;
        for (int x = 0; x < 8; ++x)
            G += (__hip_atomic_load(syncp + 640 + x, __ATOMIC_RELAXED, __HIP_MEMORY_SCOPE_AGENT) > 0);
        if (m < 1) m = 1;
        if (G < 1) G = 1;
        smeta[1] = m;
        smeta[3] = G;
    }
    __syncthreads();
    const int myx_a = smeta[0];
    const int myM_a = smeta[1];
    const int myr_a = smeta[2];
    const int G_a   = smeta[3];

    int* d1 = syncp + 1024;
    int* d2 = syncp + 1280;
    int* d3 = syncp + 1536;

    // arena slot helpers (gen s -> slot s&7; +16 keeps negatives safe)
    auto H1S = [&](int s) { return h1a + (size_t)((s + 16) & 7) * 262144; };
    auto H2S = [&](int s) { return h2a + (size_t)((s + 16) & 7) * 262144; };
    auto H3S = [&](int s) { return h3a + (size_t)((s + 16) & 7) * 131072; };

    const int col = lane & 15, du = col & 3, g = col >> 2;

    float bl1[2], bl2[2], bl3[1];
    if (isA) {
        bl2[0] = bc2[g * 1024 + (2 * sb + 0) * 4 + du];
        bl2[1] = bc2[g * 1024 + (2 * sb + 1) * 4 + du];
        bl1[0] = bl1[1] = bl3[0] = 0.f;
    } else {
        bl1[0] = bc1[g * 1024 + (2 * sb + 0) * 4 + du];
        bl1[1] = bc1[g * 1024 + (2 * sb + 1) * 4 + du];
        bl3[0] = bc3[g * 512 + sb * 4 + du];
        bl2[0] = bl2[1] = 0.f;
    }

    float c1r[2][4] = {{0.f,0.f,0.f,0.f},{0.f,0.f,0.f,0.f}};
    float c2r[2][4] = {{0.f,0.f,0.f,0.f},{0.f,0.f,0.f,0.f}};
    float c3r[1][4] = {{0.f,0.f,0.f,0.f}};

    float* h1o = out;
    float* c1o = out + 262144;
    float* h2o = out + 524288;
    float* c2o = out + 786432;
    float* h3o = out + 1048576;
    float* c3o = out + 1179648;

    // prologue: B: l1(0) from x(0) + zero slot; signal done1[0].
    if (!isA) {
        run_layer<16, 32, false, 2, 1024, 3072>(ldsw, lane,
            xs, H1S(-1), bl1, H1S(0), sb, c1r, 2 * sb, lane, wave, false, h1o, c1o);
        __syncthreads();
        if (tid == 0) signal_cnt(d1 + 0);
    }

    int rnd = 1;
    for (int t = 0; t < 128; ++t) {
        if ((t & 3) == 0)
            grid_sync(syncp, myx_a, myM_a, G_a, myr_a, rnd++);

        if (isA) {
            if (tid == 0) {
                wait_cnt(d1 + t, 128);
                if (t >= 1) wait_cnt(d2 + t - 1, 128);
                l1_inv();
            }
            __syncthreads();
            run_layer<32, 32, false, 2, 1024, 4096>(ldsw, lane,
                H1S(t), H2S(t - 1), bl2,
                H2S(t), sb, c2r, 2 * sb, lane, wave, t == 127, h2o, c2o);
            __syncthreads();
            if (tid == 0) signal_cnt(d2 + t);
        } else {
            if (t < 127) {
                if (tid == 0) { wait_cnt(d1 + t, 128); l1_inv(); }
                __syncthreads();
                run_layer<16, 32, false, 2, 1024, 3072>(ldsw, lane,
                    xs + (size_t)(t + 1) * 131072, H1S(t), bl1,
                    H1S(t + 1), sb, c1r, 2 * sb, lane, wave, (t + 1) == 127, h1o, c1o);
                __syncthreads();
                if (tid == 0) signal_cnt(d1 + t + 1);
            }
            if (t >= 1) {
                if (tid == 0) {
                    wait_cnt(d2 + t - 1, 128);
                    if (t >= 2) wait_cnt(d3 + t - 2, 128);
                    l1_inv();
                }
                __syncthreads();
                run_layer<32, 16, true, 1, 512, 0>(ldsw, 6144 + lane,
                    H2S(t - 1), H3S(t - 2), bl3,
                    H3S(t - 1), sb, c3r, sb, lane, wave, false, h3o, c3o);
                __syncthreads();
                if (tid == 0) signal_cnt(d3 + t - 1);
            }
        }
    }

    // epilogue: B: l3(127), final.
    if (!isA) {
        if (tid == 0) {
            wait_cnt(d2 + 127, 128);
            wait_cnt(d3 + 126, 128);
            l1_inv();
        }
        __syncthreads();
        run_layer<32, 16, true, 1, 512, 0>(ldsw, 6144 + lane,
            H2S(127), H3S(126), bl3, H3S(127), sb, c3r, sb, lane, wave, true, h3o, c3o);
    }
}

// ---------------- launch ----------------
extern "C" void kernel_launch(void* const* d_in, const int* in_sizes, int n_in,
                              void* d_out, int out_size, void* d_ws, size_t ws_size,
                              hipStream_t stream) {
    const float* x    = (const float*)d_in[0];
    const float* Wih1 = (const float*)d_in[1];
    const float* Whh1 = (const float*)d_in[2];
    const float* bih1 = (const float*)d_in[3];
    const float* bhh1 = (const float*)d_in[4];
    const float* Wih2 = (const float*)d_in[5];
    const float* Whh2 = (const float*)d_in[6];
    const float* bih2 = (const float*)d_in[7];
    const float* bhh2 = (const float*)d_in[8];
    const float* Wih3 = (const float*)d_in[9];
    const float* Whh3 = (const float*)d_in[10];
    const float* bih3 = (const float*)d_in[11];
    const float* bhh3 = (const float*)d_in[12];
    float* out = (float*)d_out;

    char* p = (char*)d_ws;
    auto alloc = [&](size_t bytes) {
        char* r = p;
        p += (bytes + 255) & ~(size_t)255;
        return r;
    };
    __hip_bfloat16* xs  = (__hip_bfloat16*)alloc((size_t)128 * 64 * 256 * 8 * 2);
    __hip_bfloat16* w1f = (__hip_bfloat16*)alloc((size_t)256 * 48 * 64 * 8 * 2);
    __hip_bfloat16* w2f = (__hip_bfloat16*)alloc((size_t)256 * 64 * 64 * 8 * 2);
    __hip_bfloat16* w3f = (__hip_bfloat16*)alloc((size_t)128 * 48 * 64 * 8 * 2);
    float* bc1 = (float*)alloc(4096 * 4);
    float* bc2 = (float*)alloc(4096 * 4);
    float* bc3 = (float*)alloc(2048 * 4);
    __hip_bfloat16* h1a = (__hip_bfloat16*)alloc((size_t)8 * 262144 * 2);
    __hip_bfloat16* h2a = (__hip_bfloat16*)alloc((size_t)8 * 262144 * 2);
    __hip_bfloat16* h3a = (__hip_bfloat16*)alloc((size_t)8 * 131072 * 2);
    int* syncp = (int*)alloc(32768);

    auto blocks = [](int n) { return (n + 255) / 256; };

    pack_frag_kernel<512, 1024, 1024><<<blocks(256 * 48 * 64), 256, 0, stream>>>(Wih1, Whh1, w1f);
    pack_frag_kernel<1024, 1024, 1024><<<blocks(256 * 64 * 64), 256, 0, stream>>>(Wih2, Whh2, w2f);
    pack_frag_kernel<1024, 512, 512><<<blocks(128 * 48 * 64), 256, 0, stream>>>(Wih3, Whh3, w3f);
    pack_bias_kernel<<<blocks(4096), 256, 0, stream>>>(bih1, bhh1, 4096, bc1);
    pack_bias_kernel<<<blocks(4096), 256, 0, stream>>>(bih2, bhh2, 4096, bc2);
    pack_bias_kernel<<<blocks(2048), 256, 0, stream>>>(bih3, bhh3, 2048, bc3);
    x_to_slab_kernel<<<blocks(128 * 256 * 512), 256, 0, stream>>>(x, xs);
    zero_f32_kernel<<<blocks(1048576), 256, 0, stream>>>((float*)h1a, 1048576);
    zero_f32_kernel<<<blocks(1048576), 256, 0, stream>>>((float*)h2a, 1048576);
    zero_f32_kernel<<<blocks(524288), 256, 0, stream>>>((float*)h3a, 524288);
    zero_i32_kernel<<<blocks(8192), 256, 0, stream>>>(syncp, 8192);

    lstm_persistent<<<NBLK, NTHR, 0, stream>>>(xs, w1f, w2f, w3f, bc1, bc2, bc3,
                                               h1a, h2a, h3a, out, syncp);
}